// Round 3
// baseline (262.792 us; speedup 1.0000x reference)
//
#include <hip/hip_runtime.h>
#include <hip/hip_bf16.h>
#include <stdint.h>

// Problem constants (fixed by reference)
#define T_TASKS 8
#define DM      1024
#define HID     1024
#define NC      100
#define NCP     128
#define BATCH   8192
#define MPAD    9216      // 8192 + 8*128 worst-case 128-aligned padding

typedef __bf16 bf16x8 __attribute__((ext_vector_type(8)));
typedef float  f32x4  __attribute__((ext_vector_type(4)));

__device__ __forceinline__ unsigned short f2bf(float f) {
  __hip_bfloat16 h = __float2bfloat16(f);
  return __builtin_bit_cast(unsigned short, h);
}

// ---------------------------------------------------------------------------
// init: zero d_out (for split-K atomics), perm = -1, gmeta = 0.
// ---------------------------------------------------------------------------
__global__ void init_k(float* __restrict__ out, int* __restrict__ perm,
                       int* __restrict__ gmeta) {
  const int gid = blockIdx.x * 256 + threadIdx.x;
  const uint4 z  = {0u, 0u, 0u, 0u};
  const uint4 m1 = {0xFFFFFFFFu, 0xFFFFFFFFu, 0xFFFFFFFFu, 0xFFFFFFFFu};
  uint4* o4 = (uint4*)out;
  for (int i = gid; i < (BATCH * NC) / 4; i += 512 * 256) o4[i] = z;
  uint4* p4 = (uint4*)perm;
  for (int i = gid; i < MPAD / 4; i += 512 * 256) p4[i] = m1;
  if (gid < 16) gmeta[gid] = 0;
}

// ---------------------------------------------------------------------------
// count: per-block LDS histogram -> 8 global atomics. grid 32 x 256.
// ---------------------------------------------------------------------------
__global__ void count_k(const int* __restrict__ task_id, int* __restrict__ gmeta) {
  __shared__ int h[T_TASKS];
  const int tid = threadIdx.x;
  if (tid < T_TASKS) h[tid] = 0;
  __syncthreads();
  atomicAdd(&h[task_id[blockIdx.x * 256 + tid]], 1);
  __syncthreads();
  if (tid < T_TASKS) atomicAdd(&gmeta[tid], h[tid]);
}

// ---------------------------------------------------------------------------
// scatter: starts from complete gcnt; per-block local slots + one global
// range reservation per task per block. grid 32 x 256.
// ---------------------------------------------------------------------------
__global__ void scatter_k(const int* __restrict__ task_id, int* __restrict__ gmeta,
                          int* __restrict__ perm, int* __restrict__ starts) {
  __shared__ int h[T_TASKS];
  __shared__ int base[T_TASKS];
  __shared__ int sst[T_TASKS + 1];
  const int tid = threadIdx.x;
  if (tid < T_TASKS) h[tid] = 0;
  if (tid == 0) {
    int off = 0;
    for (int t = 0; t < T_TASKS; ++t) {
      sst[t] = off;
      off += (gmeta[t] + 127) & ~127;
    }
    sst[T_TASKS] = off;
  }
  __syncthreads();
  const int r = blockIdx.x * 256 + tid;
  const int t = task_id[r];
  const int slot = atomicAdd(&h[t], 1);
  __syncthreads();
  if (tid < T_TASKS) base[tid] = atomicAdd(&gmeta[8 + tid], h[tid]);
  __syncthreads();
  perm[sst[t] + base[t] + slot] = r;
  if (blockIdx.x == 0 && tid <= T_TASKS) starts[tid] = sst[tid];
}

// ---------------------------------------------------------------------------
// gather x rows into permuted bf16 buffer XP (zeros for pads). grid MPAD x 256.
// ---------------------------------------------------------------------------
__global__ void gather_x(const float* __restrict__ x,
                         const int* __restrict__ perm,
                         unsigned short* __restrict__ XP) {
  const int p = blockIdx.x;
  const int r = perm[p];
  const int c = threadIdx.x * 4;
  ushort4 v;
  if (r >= 0) {
    const float4 f = *(const float4*)(x + (size_t)r * DM + c);
    v.x = f2bf(f.x); v.y = f2bf(f.y); v.z = f2bf(f.z); v.w = f2bf(f.w);
  } else {
    v.x = 0; v.y = 0; v.z = 0; v.w = 0;
  }
  *(ushort4*)(XP + (size_t)p * DM + c) = v;
}

// ---------------------------------------------------------------------------
// W1 [t][d][h] fp32 -> W1T [t][h][d] bf16  (LDS-tiled 64x64)
// ---------------------------------------------------------------------------
__global__ void transpose_w1(const float* __restrict__ W1,
                             unsigned short* __restrict__ W1T) {
  __shared__ unsigned short tile[64][65];
  const int t  = blockIdx.z;
  const int d0 = blockIdx.x * 64;
  const int h0 = blockIdx.y * 64;
  const int tid = threadIdx.x;
  const float* src = W1 + (size_t)t * DM * HID;
  unsigned short* dst = W1T + (size_t)t * HID * DM;
#pragma unroll
  for (int i = 0; i < 16; ++i) {
    int idx = tid + 256 * i;
    int ld = idx >> 6, lh = idx & 63;
    tile[lh][ld] = f2bf(src[(size_t)(d0 + ld) * HID + h0 + lh]);
  }
  __syncthreads();
#pragma unroll
  for (int i = 0; i < 16; ++i) {
    int idx = tid + 256 * i;
    int lh = idx >> 6, ld = idx & 63;
    dst[(size_t)(h0 + lh) * DM + d0 + ld] = tile[lh][ld];
  }
}

// ---------------------------------------------------------------------------
// W2 [t][h][c<100] fp32 -> W2T [t][c<128][h] bf16 (pad cols w/ 0)
// ---------------------------------------------------------------------------
__global__ void transpose_w2(const float* __restrict__ W2,
                             unsigned short* __restrict__ W2T) {
  __shared__ unsigned short tile[64][65];
  const int t  = blockIdx.z;
  const int c0 = blockIdx.x * 64;
  const int h0 = blockIdx.y * 64;
  const int tid = threadIdx.x;
  const float* src = W2 + (size_t)t * HID * NC;
  unsigned short* dst = W2T + (size_t)t * NCP * HID;
#pragma unroll
  for (int i = 0; i < 16; ++i) {
    int idx = tid + 256 * i;
    int lh = idx >> 6, lc = idx & 63;
    int c = c0 + lc;
    float f = (c < NC) ? src[(size_t)(h0 + lh) * NC + c] : 0.f;
    tile[lc][lh] = f2bf(f);
  }
  __syncthreads();
#pragma unroll
  for (int i = 0; i < 16; ++i) {
    int idx = tid + 256 * i;
    int lc = idx >> 6, lh = idx & 63;
    dst[(size_t)(c0 + lc) * HID + h0 + lh] = tile[lc][lh];
  }
}

// ---------------------------------------------------------------------------
// GEMM1: register-tiled, LDS-free, barrier-free. 1 wave/block, 64x64 tile.
// grid (MPAD/64=144, HID/64=16). Fragments loaded global->VGPR directly
// (16B/lane, 64B segments across quads); explicit ping-pong prefetch so
// loads(k+32) overlap MFMAs(k). No __syncthreads -> no vmcnt(0) drain.
// Epilogue: +b1, ReLU, bf16 store to HB (permuted row space).
// ---------------------------------------------------------------------------
__global__ __launch_bounds__(64, 2) void gemm1_reg(
    const unsigned short* __restrict__ XP,     // [MPAD][1024] bf16 (permuted)
    const unsigned short* __restrict__ W1T,    // [T][HID][1024] bf16
    const float* __restrict__ b1,              // [T][HID]
    const int* __restrict__ starts,            // [9]
    unsigned short* __restrict__ HB)           // [MPAD][1024] bf16 out
{
  const int p0 = blockIdx.x * 64;
  const int n0 = blockIdx.y * 64;
  const int lane = threadIdx.x;
  const int lr   = lane & 15;
  const int quad = lane >> 4;

  int task = 0;
#pragma unroll
  for (int t = 1; t < T_TASKS; ++t)
    if (p0 >= starts[t]) task = t;

  // Fragment row pointers (A: m = lr within each 16-tile; B: n = lr).
  const unsigned short* pA[4];
  const unsigned short* pB[4];
#pragma unroll
  for (int i = 0; i < 4; ++i) {
    pA[i] = XP + (size_t)(p0 + i * 16 + lr) * 1024 + quad * 8;
    pB[i] = W1T + ((size_t)task * HID + n0 + i * 16 + lr) * 1024 + quad * 8;
  }

  f32x4 acc[4][4];
#pragma unroll
  for (int i = 0; i < 4; ++i)
#pragma unroll
    for (int j = 0; j < 4; ++j) acc[i][j] = (f32x4){0.f, 0.f, 0.f, 0.f};

  bf16x8 a0[4], b0[4], a1[4], b1f[4];
#pragma unroll
  for (int i = 0; i < 4; ++i) { a0[i] = *(const bf16x8*)(pA[i]); b0[i] = *(const bf16x8*)(pB[i]); }

  // K-loop: step 64, two ping-pong stages. Final prefetch over-reads <=64B
  // past the row end (still inside d_ws regions) and is never consumed.
  for (int k0 = 0; k0 < 1024; k0 += 64) {
#pragma unroll
    for (int i = 0; i < 4; ++i) { a1[i] = *(const bf16x8*)(pA[i] + k0 + 32); b1f[i] = *(const bf16x8*)(pB[i] + k0 + 32); }
#pragma unroll
    for (int i = 0; i < 4; ++i)
#pragma unroll
      for (int j = 0; j < 4; ++j)
        acc[i][j] = __builtin_amdgcn_mfma_f32_16x16x32_bf16(a0[i], b0[j], acc[i][j], 0, 0, 0);
#pragma unroll
    for (int i = 0; i < 4; ++i) { a0[i] = *(const bf16x8*)(pA[i] + k0 + 64); b0[i] = *(const bf16x8*)(pB[i] + k0 + 64); }
#pragma unroll
    for (int i = 0; i < 4; ++i)
#pragma unroll
      for (int j = 0; j < 4; ++j)
        acc[i][j] = __builtin_amdgcn_mfma_f32_16x16x32_bf16(a1[i], b1f[j], acc[i][j], 0, 0, 0);
  }

  // Epilogue. C/D layout: col = lane&15, row = quad*4 + reg  [m89]
  const float* bv = b1 + (size_t)task * HID;
#pragma unroll
  for (int i = 0; i < 4; ++i) {
#pragma unroll
    for (int r = 0; r < 4; ++r) {
      const int row = p0 + i * 16 + quad * 4 + r;
#pragma unroll
      for (int j = 0; j < 4; ++j) {
        const int col = n0 + j * 16 + lr;
        float v = acc[i][j][r] + bv[col];
        v = v > 0.f ? v : 0.f;
        HB[(size_t)row * 1024 + col] = f2bf(v);
      }
    }
  }
}

// ---------------------------------------------------------------------------
// GEMM2: register-tiled, barrier-free, split-K x8. 1 wave/block, 64x64 tile.
// grid (144, 2, 8); z = K-split (128 K each). Epilogue scatters valid rows
// to d_out (fp32) via perm with unsafeAtomicAdd; +b2 only on split 0.
// ---------------------------------------------------------------------------
__global__ __launch_bounds__(64, 2) void gemm2_reg(
    const unsigned short* __restrict__ HB,     // [MPAD][1024] bf16
    const unsigned short* __restrict__ W2T,    // [T][NCP][1024] bf16
    const float* __restrict__ b2,              // [T][NC]
    const int* __restrict__ starts,            // [9]
    const int* __restrict__ perm,              // [MPAD]
    float* __restrict__ Out)                   // [BATCH][NC] fp32
{
  const int p0   = blockIdx.x * 64;
  const int n0   = blockIdx.y * 64;
  const int kbeg = blockIdx.z * 128;
  const int lane = threadIdx.x;
  const int lr   = lane & 15;
  const int quad = lane >> 4;

  int task = 0;
#pragma unroll
  for (int t = 1; t < T_TASKS; ++t)
    if (p0 >= starts[t]) task = t;

  const unsigned short* pA[4];
  const unsigned short* pB[4];
#pragma unroll
  for (int i = 0; i < 4; ++i) {
    pA[i] = HB + (size_t)(p0 + i * 16 + lr) * 1024 + kbeg + quad * 8;
    pB[i] = W2T + ((size_t)task * NCP + n0 + i * 16 + lr) * 1024 + kbeg + quad * 8;
  }

  f32x4 acc[4][4];
#pragma unroll
  for (int i = 0; i < 4; ++i)
#pragma unroll
    for (int j = 0; j < 4; ++j) acc[i][j] = (f32x4){0.f, 0.f, 0.f, 0.f};

  bf16x8 a0[4], b0[4], a1[4], b1f[4];
#pragma unroll
  for (int i = 0; i < 4; ++i) { a0[i] = *(const bf16x8*)(pA[i]); b0[i] = *(const bf16x8*)(pB[i]); }
#pragma unroll
  for (int i = 0; i < 4; ++i) { a1[i] = *(const bf16x8*)(pA[i] + 32); b1f[i] = *(const bf16x8*)(pB[i] + 32); }
#pragma unroll
  for (int kk = 0; kk < 4; ++kk) {
    if (kk < 2) {
      // prefetch kk+2 into the buffer just consumed next round
    }
#pragma unroll
    for (int i = 0; i < 4; ++i)
#pragma unroll
      for (int j = 0; j < 4; ++j)
        acc[i][j] = __builtin_amdgcn_mfma_f32_16x16x32_bf16(
            (kk & 1) ? a1[i] : a0[i], (kk & 1) ? b1f[j] : b0[j], acc[i][j], 0, 0, 0);
    if (kk == 0) {
#pragma unroll
      for (int i = 0; i < 4; ++i) { a0[i] = *(const bf16x8*)(pA[i] + 64); b0[i] = *(const bf16x8*)(pB[i] + 64); }
    } else if (kk == 1) {
#pragma unroll
      for (int i = 0; i < 4; ++i) { a1[i] = *(const bf16x8*)(pA[i] + 96); b1f[i] = *(const bf16x8*)(pB[i] + 96); }
    }
  }

  const float* bv = b2 + (size_t)task * NC;
  const bool addb = (kbeg == 0);
#pragma unroll
  for (int i = 0; i < 4; ++i) {
#pragma unroll
    for (int r = 0; r < 4; ++r) {
      const int prow = p0 + i * 16 + quad * 4 + r;
      const int orig = perm[prow];
      if (orig < 0) continue;
#pragma unroll
      for (int j = 0; j < 4; ++j) {
        const int col = n0 + j * 16 + lr;
        if (col < NC) {
          float v = acc[i][j][r];
          if (addb) v += bv[col];
          unsafeAtomicAdd(&Out[(size_t)orig * NC + col], v);
        }
      }
    }
  }
}

// ---------------------------------------------------------------------------
// Workspace layout (bytes):
//   perm   int[9216]            @ 0           (36864)
//   gmeta  int[16]              @ 36864
//   starts int[9]               @ 36928
//   XP     bf16[9216*1024]      @ 65536       (18874368)
//   W1T    bf16[8*1024*1024]    @ 18939904    (16777216)
//   W2T    bf16[8*128*1024]     @ 35717120    (2097152)
//   HB     bf16[9216*1024]      @ 37814272    (18874368)  end 56688640
// ---------------------------------------------------------------------------
extern "C" void kernel_launch(void* const* d_in, const int* in_sizes, int n_in,
                              void* d_out, int out_size, void* d_ws, size_t ws_size,
                              hipStream_t stream) {
  const float* x       = (const float*)d_in[0];
  const int*   task_id = (const int*)d_in[1];
  const float* W1      = (const float*)d_in[2];
  const float* b1      = (const float*)d_in[3];
  const float* W2      = (const float*)d_in[4];
  const float* b2      = (const float*)d_in[5];
  float* out = (float*)d_out;

  char* ws = (char*)d_ws;
  int* perm   = (int*)(ws + 0);
  int* gmeta  = (int*)(ws + 36864);
  int* starts = (int*)(ws + 36928);
  unsigned short* XP  = (unsigned short*)(ws + 65536);
  unsigned short* W1T = (unsigned short*)(ws + 18939904);
  unsigned short* W2T = (unsigned short*)(ws + 35717120);
  unsigned short* HB  = (unsigned short*)(ws + 37814272);

  init_k<<<512, 256, 0, stream>>>(out, perm, gmeta);
  count_k<<<32, 256, 0, stream>>>(task_id, gmeta);
  scatter_k<<<32, 256, 0, stream>>>(task_id, gmeta, perm, starts);
  gather_x<<<MPAD, 256, 0, stream>>>(x, perm, XP);
  transpose_w1<<<dim3(16, 16, T_TASKS), 256, 0, stream>>>(W1, W1T);
  transpose_w2<<<dim3(2, 16, T_TASKS), 256, 0, stream>>>(W2, W2T);
  gemm1_reg<<<dim3(MPAD / 64, HID / 64), 64, 0, stream>>>(XP, W1T, b1, starts, HB);
  gemm2_reg<<<dim3(MPAD / 64, 2, 8), 64, 0, stream>>>(HB, W2T, b2, starts, perm, out);
}

// Round 4
// 197.193 us; speedup vs baseline: 1.3327x; 1.3327x over previous
//
#include <hip/hip_runtime.h>
#include <hip/hip_bf16.h>
#include <stdint.h>

// Problem constants (fixed by reference)
#define T_TASKS 8
#define DM      1024
#define HID     1024
#define NC      100
#define NCP     128
#define BATCH   8192
#define MPAD    9216      // 8192 + 8*128 worst-case 128-aligned padding

typedef __bf16 bf16x8 __attribute__((ext_vector_type(8)));
typedef float  f32x4  __attribute__((ext_vector_type(4)));
typedef unsigned int u32;
#define GAS __attribute__((address_space(1)))
#define LAS __attribute__((address_space(3)))

__device__ __forceinline__ unsigned short f2bf(float f) {
  __hip_bfloat16 h = __float2bfloat16(f);
  return __builtin_bit_cast(unsigned short, h);
}

// ---------------------------------------------------------------------------
// init: zero d_out (atomic target), perm = -1, gmeta = 0.
// ---------------------------------------------------------------------------
__global__ void init_k(float* __restrict__ out, int* __restrict__ perm,
                       int* __restrict__ gmeta) {
  const int gid = blockIdx.x * 256 + threadIdx.x;
  const uint4 z  = {0u, 0u, 0u, 0u};
  const uint4 m1 = {0xFFFFFFFFu, 0xFFFFFFFFu, 0xFFFFFFFFu, 0xFFFFFFFFu};
  uint4* o4 = (uint4*)out;
  for (int i = gid; i < (BATCH * NC) / 4; i += 512 * 256) o4[i] = z;
  uint4* p4 = (uint4*)perm;
  for (int i = gid; i < MPAD / 4; i += 512 * 256) p4[i] = m1;
  if (gid < 16) gmeta[gid] = 0;
}

// ---------------------------------------------------------------------------
// count: per-block LDS histogram -> 8 global atomics. grid 32 x 256.
// ---------------------------------------------------------------------------
__global__ void count_k(const int* __restrict__ task_id, int* __restrict__ gmeta) {
  __shared__ int h[T_TASKS];
  const int tid = threadIdx.x;
  if (tid < T_TASKS) h[tid] = 0;
  __syncthreads();
  atomicAdd(&h[task_id[blockIdx.x * 256 + tid]], 1);
  __syncthreads();
  if (tid < T_TASKS) atomicAdd(&gmeta[tid], h[tid]);
}

// ---------------------------------------------------------------------------
// scatter: starts from complete gcnt; per-block local slots + one global
// range reservation per task per block. grid 32 x 256.
// ---------------------------------------------------------------------------
__global__ void scatter_k(const int* __restrict__ task_id, int* __restrict__ gmeta,
                          int* __restrict__ perm, int* __restrict__ starts) {
  __shared__ int h[T_TASKS];
  __shared__ int base[T_TASKS];
  __shared__ int sst[T_TASKS + 1];
  const int tid = threadIdx.x;
  if (tid < T_TASKS) h[tid] = 0;
  if (tid == 0) {
    int off = 0;
    for (int t = 0; t < T_TASKS; ++t) {
      sst[t] = off;
      off += (gmeta[t] + 127) & ~127;
    }
    sst[T_TASKS] = off;
  }
  __syncthreads();
  const int r = blockIdx.x * 256 + tid;
  const int t = task_id[r];
  const int slot = atomicAdd(&h[t], 1);
  __syncthreads();
  if (tid < T_TASKS) base[tid] = atomicAdd(&gmeta[8 + tid], h[tid]);
  __syncthreads();
  perm[sst[t] + base[t] + slot] = r;
  if (blockIdx.x == 0 && tid <= T_TASKS) starts[tid] = sst[tid];
}

// ---------------------------------------------------------------------------
// gather+convert x rows into permuted bf16 XP (zeros for pads). grid MPAD x 256.
// ---------------------------------------------------------------------------
__global__ void gather_x(const float* __restrict__ x,
                         const int* __restrict__ perm,
                         unsigned short* __restrict__ XP) {
  const int p = blockIdx.x;
  const int r = perm[p];
  const int c = threadIdx.x * 4;
  ushort4 v;
  if (r >= 0) {
    const float4 f = *(const float4*)(x + (size_t)r * DM + c);
    v.x = f2bf(f.x); v.y = f2bf(f.y); v.z = f2bf(f.z); v.w = f2bf(f.w);
  } else {
    v.x = 0; v.y = 0; v.z = 0; v.w = 0;
  }
  *(ushort4*)(XP + (size_t)p * DM + c) = v;
}

// ---------------------------------------------------------------------------
// W1 [t][d][h] fp32 -> W1T [t][h][d] bf16  (LDS-tiled 64x64)
// ---------------------------------------------------------------------------
__global__ void transpose_w1(const float* __restrict__ W1,
                             unsigned short* __restrict__ W1T) {
  __shared__ unsigned short tile[64][65];
  const int t  = blockIdx.z;
  const int d0 = blockIdx.x * 64;
  const int h0 = blockIdx.y * 64;
  const int tid = threadIdx.x;
  const float* src = W1 + (size_t)t * DM * HID;
  unsigned short* dst = W1T + (size_t)t * HID * DM;
#pragma unroll
  for (int i = 0; i < 16; ++i) {
    int idx = tid + 256 * i;
    int ld = idx >> 6, lh = idx & 63;
    tile[lh][ld] = f2bf(src[(size_t)(d0 + ld) * HID + h0 + lh]);
  }
  __syncthreads();
#pragma unroll
  for (int i = 0; i < 16; ++i) {
    int idx = tid + 256 * i;
    int lh = idx >> 6, ld = idx & 63;
    dst[(size_t)(h0 + lh) * DM + d0 + ld] = tile[lh][ld];
  }
}

// ---------------------------------------------------------------------------
// W2 [t][h][c<100] fp32 -> W2T [t][c<128][h] bf16 (pad cols w/ 0)
// ---------------------------------------------------------------------------
__global__ void transpose_w2(const float* __restrict__ W2,
                             unsigned short* __restrict__ W2T) {
  __shared__ unsigned short tile[64][65];
  const int t  = blockIdx.z;
  const int c0 = blockIdx.x * 64;
  const int h0 = blockIdx.y * 64;
  const int tid = threadIdx.x;
  const float* src = W2 + (size_t)t * HID * NC;
  unsigned short* dst = W2T + (size_t)t * NCP * HID;
#pragma unroll
  for (int i = 0; i < 16; ++i) {
    int idx = tid + 256 * i;
    int lh = idx >> 6, lc = idx & 63;
    int c = c0 + lc;
    float f = (c < NC) ? src[(size_t)(h0 + lh) * NC + c] : 0.f;
    tile[lc][lh] = f2bf(f);
  }
  __syncthreads();
#pragma unroll
  for (int i = 0; i < 16; ++i) {
    int idx = tid + 256 * i;
    int lc = idx >> 6, lh = idx & 63;
    dst[(size_t)(c0 + lc) * HID + h0 + lh] = tile[lc][lh];
  }
}

// ---------------------------------------------------------------------------
// Fused MLP kernel. grid (MPAD/64 = 144, HID/128 = 8), 256 threads = 4 waves.
// Block tile: 64 (M) x 128 (N of layer-1), BK=64, LDS 24KB -> ~6 blocks/CU.
// Waves split N: wave w handles cols [w*32, w*32+32) as 4x2 of 16x16x32 MFMA.
// Staging: global_load_lds width=16, XOR chunk swizzle (chunk j holds global
// k-chunk j^(row&7)) -> conflict-free ds_read_b128 (verified 0 conflicts r2).
// After K-loop: h = relu(acc + b1) -> bf16 -> LDS (stride 136 = conflict-free
// 16-lane b128 reads), then 64x128 h-chunk x W2T[k-slice n0..n0+127] -> 64x128
// partial logits -> unsafeAtomicAdd scatter to out via perm (+b2 on n0==0).
// This fuses GEMM2 (each out element gets 8 partials) and eliminates HB.
// ---------------------------------------------------------------------------
__global__ __launch_bounds__(256, 4) void gemm_fused(
    const unsigned short* __restrict__ XP,     // [MPAD][1024] bf16 permuted
    const unsigned short* __restrict__ W1T,    // [T][HID][1024] bf16
    const unsigned short* __restrict__ W2T,    // [T][NCP][1024] bf16
    const float* __restrict__ b1,              // [T][HID]
    const float* __restrict__ b2,              // [T][NC]
    const int* __restrict__ starts,            // [9]
    const int* __restrict__ perm,              // [MPAD]
    float* __restrict__ Out)                   // [BATCH][NC] fp32 (zeroed)
{
  __shared__ __align__(16) unsigned short smem[12288];   // 24 KB
  unsigned short* As = smem;                   // [64 rows][8 chunks][8 shorts]
  unsigned short* Bs = smem + 4096;            // [128 rows][8 chunks][8 shorts]

  const int tid = threadIdx.x;
  const int p0  = blockIdx.x * 64;
  const int n0  = blockIdx.y * 128;

  int task = 0;
#pragma unroll
  for (int t = 1; t < T_TASKS; ++t)
    if (p0 >= starts[t]) task = t;

  const int lane = tid & 63;
  const int wn   = (tid >> 6) * 32;            // wave's N offset within tile
  const int lr   = lane & 15;
  const int quad = lane >> 4;

  // --- staging pointers (16B chunk per thread per 256): XOR swizzle ---
  const int crow = tid >> 3;                   // 0..31
  const int ccol = tid & 7;
  const unsigned short* pA[2];
  const unsigned short* pB[4];
#pragma unroll
  for (int i = 0; i < 2; ++i) {
    const int row = crow + 32 * i;
    pA[i] = XP + (size_t)(p0 + row) * 1024 + (ccol ^ (row & 7)) * 8;
  }
#pragma unroll
  for (int i = 0; i < 4; ++i) {
    const int row = crow + 32 * i;
    pB[i] = W1T + ((size_t)task * HID + n0 + row) * 1024 + (ccol ^ (row & 7)) * 8;
  }

  f32x4 acc[4][2];
#pragma unroll
  for (int i = 0; i < 4; ++i)
#pragma unroll
    for (int j = 0; j < 2; ++j) acc[i][j] = (f32x4){0.f, 0.f, 0.f, 0.f};

  const int swl = lr & 7;

  for (int k0 = 0; k0 < 1024; k0 += 64) {
#pragma unroll
    for (int i = 0; i < 2; ++i)
      __builtin_amdgcn_global_load_lds((const GAS u32*)(pA[i] + k0),
                                       (LAS u32*)&As[(tid + 256 * i) * 8], 16, 0, 0);
#pragma unroll
    for (int i = 0; i < 4; ++i)
      __builtin_amdgcn_global_load_lds((const GAS u32*)(pB[i] + k0),
                                       (LAS u32*)&Bs[(tid + 256 * i) * 8], 16, 0, 0);
    __syncthreads();
#pragma unroll
    for (int kk = 0; kk < 2; ++kk) {
      const int swc = (kk * 4 + quad) ^ swl;
      bf16x8 a[4], b[2];
#pragma unroll
      for (int i = 0; i < 4; ++i)
        a[i] = *(const bf16x8*)&As[((i * 16 + lr) * 8 + swc) * 8];
#pragma unroll
      for (int j = 0; j < 2; ++j)
        b[j] = *(const bf16x8*)&Bs[((wn + j * 16 + lr) * 8 + swc) * 8];
#pragma unroll
      for (int i = 0; i < 4; ++i)
#pragma unroll
        for (int j = 0; j < 2; ++j)
          acc[i][j] = __builtin_amdgcn_mfma_f32_16x16x32_bf16(a[i], b[j], acc[i][j], 0, 0, 0);
    }
    __syncthreads();
  }

  // --- issue W2 fragment loads early (B-operand of mm2, k-slice = n0 tile) ---
  bf16x8 w2f[2][4];
#pragma unroll
  for (int j = 0; j < 2; ++j) {
    const unsigned short* base =
        W2T + ((size_t)task * NCP + wn + j * 16 + lr) * 1024 + n0 + quad * 8;
#pragma unroll
    for (int kk = 0; kk < 4; ++kk)
      w2f[j][kk] = *(const bf16x8*)(base + kk * 32);
  }

  // --- h = relu(acc + b1) -> bf16 -> LDS [64][136] (C-layout scatter) ---
  unsigned short* hS = smem;                   // reuse; 64*136*2 = 17408 <= 24576
  const float* bv = b1 + (size_t)task * HID + n0;
#pragma unroll
  for (int i = 0; i < 4; ++i) {
#pragma unroll
    for (int r = 0; r < 4; ++r) {
      const int row = i * 16 + quad * 4 + r;
#pragma unroll
      for (int j = 0; j < 2; ++j) {
        const int col = wn + j * 16 + lr;
        float v = acc[i][j][r] + bv[col];
        v = v > 0.f ? v : 0.f;
        hS[row * 136 + col] = f2bf(v);
      }
    }
  }
  __syncthreads();

  // --- mm2: 64x128(h) x 128x128(W2 slice) -> 64x128 partial logits ---
  f32x4 acc2[4][2];
#pragma unroll
  for (int i = 0; i < 4; ++i)
#pragma unroll
    for (int j = 0; j < 2; ++j) acc2[i][j] = (f32x4){0.f, 0.f, 0.f, 0.f};
#pragma unroll
  for (int kk = 0; kk < 4; ++kk) {
#pragma unroll
    for (int i = 0; i < 4; ++i) {
      const bf16x8 a2 = *(const bf16x8*)&hS[(i * 16 + lr) * 136 + kk * 32 + quad * 8];
#pragma unroll
      for (int j = 0; j < 2; ++j)
        acc2[i][j] = __builtin_amdgcn_mfma_f32_16x16x32_bf16(a2, w2f[j][kk], acc2[i][j], 0, 0, 0);
    }
  }

  // --- scatter partial logits to out (fp32 atomics); +b2 once (n0==0) ---
  const float* bv2 = b2 + (size_t)task * NC;
  const bool addb = (n0 == 0);
#pragma unroll
  for (int i = 0; i < 4; ++i) {
#pragma unroll
    for (int r = 0; r < 4; ++r) {
      const int prow = p0 + i * 16 + quad * 4 + r;
      const int orig = perm[prow];
      if (orig < 0) continue;
#pragma unroll
      for (int j = 0; j < 2; ++j) {
        const int col = wn + j * 16 + lr;
        if (col < NC) {
          float v = acc2[i][j][r];
          if (addb) v += bv2[col];
          unsafeAtomicAdd(&Out[(size_t)orig * NC + col], v);
        }
      }
    }
  }
}

// ---------------------------------------------------------------------------
// Workspace layout (bytes):
//   perm   int[9216]            @ 0           (36864)
//   gmeta  int[16]              @ 36864
//   starts int[9]               @ 36928
//   XP     bf16[9216*1024]      @ 65536       (18874368)
//   W1T    bf16[8*1024*1024]    @ 18939904    (16777216)
//   W2T    bf16[8*128*1024]     @ 35717120    (2097152)   end 37814272 (~36MB)
// ---------------------------------------------------------------------------
extern "C" void kernel_launch(void* const* d_in, const int* in_sizes, int n_in,
                              void* d_out, int out_size, void* d_ws, size_t ws_size,
                              hipStream_t stream) {
  const float* x       = (const float*)d_in[0];
  const int*   task_id = (const int*)d_in[1];
  const float* W1      = (const float*)d_in[2];
  const float* b1      = (const float*)d_in[3];
  const float* W2      = (const float*)d_in[4];
  const float* b2      = (const float*)d_in[5];
  float* out = (float*)d_out;

  char* ws = (char*)d_ws;
  int* perm   = (int*)(ws + 0);
  int* gmeta  = (int*)(ws + 36864);
  int* starts = (int*)(ws + 36928);
  unsigned short* XP  = (unsigned short*)(ws + 65536);
  unsigned short* W1T = (unsigned short*)(ws + 18939904);
  unsigned short* W2T = (unsigned short*)(ws + 35717120);

  init_k<<<512, 256, 0, stream>>>(out, perm, gmeta);
  count_k<<<32, 256, 0, stream>>>(task_id, gmeta);
  scatter_k<<<32, 256, 0, stream>>>(task_id, gmeta, perm, starts);
  gather_x<<<MPAD, 256, 0, stream>>>(x, perm, XP);
  transpose_w1<<<dim3(16, 16, T_TASKS), 256, 0, stream>>>(W1, W1T);
  transpose_w2<<<dim3(2, 16, T_TASKS), 256, 0, stream>>>(W2, W2T);
  gemm_fused<<<dim3(MPAD / 64, HID / 128), 256, 0, stream>>>(
      XP, W1T, W2T, b1, b2, starts, perm, out);
}